// Round 13
// baseline (64.220 us; speedup 1.0000x reference)
//
#include <hip/hip_runtime.h>
#include <hip/hip_bf16.h>

#define Ls 256
#define Kk 9
#define Bb 512

typedef short s16x8 __attribute__((ext_vector_type(8)));
typedef float f32x4 __attribute__((ext_vector_type(4)));

__device__ __forceinline__ unsigned short f2bf(float f) {
    __hip_bfloat16 h = __float2bfloat16(f);
    return *reinterpret_cast<unsigned short*>(&h);
}
__device__ __forceinline__ unsigned pk2bf(float a, float b) {
    __hip_bfloat162 h = __float22bfloat162_rn(make_float2(a, b));
    return *reinterpret_cast<unsigned*>(&h);
}

// XOR swizzle on byte addr bits 4-6, function of row&15 only.
#define SWZ(row) (((((row)&7)<<4)) ^ ((((row)&8))<<2))

// ---- weight prep: pack w1/w2/w3/wd into bf16 MFMA fragments ----
__global__ __launch_bounds__(256) void kw_prep(
    const float* __restrict__ w1, const float* __restrict__ w2, const float* __restrict__ w3,
    const float* __restrict__ wd, uint4* __restrict__ wfrag)
{
    const int gid = blockIdx.x * 256 + threadIdx.x;
    const int frag = gid >> 6;
    const int lane = gid & 63;
    if (frag >= 196) return;
    const int kb = (lane >> 4) * 8;
    const int nl = lane & 15;
    float v[8];
    if (frag < 48) {
        int nt = frag & 3, kc = (frag >> 2) & 3, t = frag >> 4;
        int n = nt * 16 + nl;
        #pragma unroll
        for (int j = 0; j < 8; ++j) v[j] = w1[(t * 128 + kc * 32 + kb + j) * 64 + n];
    } else if (frag < 96) {
        int f = frag - 48; int nt = f & 7, kc = (f >> 3) & 1, t = f >> 4;
        int n = nt * 16 + nl;
        #pragma unroll
        for (int j = 0; j < 8; ++j) v[j] = w2[(t * 64 + kc * 32 + kb + j) * 128 + n];
    } else if (frag < 192) {
        int f = frag - 96; int nt = f & 7, kc = (f >> 3) & 3, t = f >> 5;
        int n = nt * 16 + nl;
        #pragma unroll
        for (int j = 0; j < 8; ++j) v[j] = w3[(t * 128 + kc * 32 + kb + j) * 128 + n];
    } else {
        int kc = frag - 192;
        #pragma unroll
        for (int j = 0; j < 8; ++j) v[j] = (nl < Kk) ? wd[(kc * 32 + kb + j) * Kk + nl] : 0.f;
    }
    uint4 o;
    o.x = (unsigned)f2bf(v[0]) | ((unsigned)f2bf(v[1]) << 16);
    o.y = (unsigned)f2bf(v[2]) | ((unsigned)f2bf(v[3]) << 16);
    o.z = (unsigned)f2bf(v[4]) | ((unsigned)f2bf(v[5]) << 16);
    o.w = (unsigned)f2bf(v[6]) | ((unsigned)f2bf(v[7]) << 16);
    wfrag[frag * 64 + lane] = o;
}

// ---- fused embed + conv1 + conv2 + conv3(dil2) + dense(MFMA) ----
// R13 = R12 with conv1 pos-split (R7 tiling, verified) + R8 batched wf loads:
// balances LDS (~500KB/block) vs L2-weight (~256KB/block) pipes.
#define X1_OFF  20992
#define X3_OFF  20992
#define SMEM_BYTES (20992 + 64 * 256)   // 37376 -> 4 blocks/CU

__global__ __launch_bounds__(256, 4) void kmain(
    const int* __restrict__ text, const float* __restrict__ embed,
    const uint4* __restrict__ wfrag,
    const float* __restrict__ b1, const float* __restrict__ b2, const float* __restrict__ b3,
    const float* __restrict__ bd,
    float* __restrict__ logits)
{
    __shared__ __align__(16) char smem[SMEM_BYTES];
    const int b = blockIdx.y, l0 = blockIdx.x * 64;
    const int tid = threadIdx.x;
    const int lane = tid & 63, wv = tid >> 6;
    const int nl = lane & 15, kg = lane >> 4;
    const int mh = wv & 1, nh = wv >> 1;
    const int nt0 = nh ? 3 : 0;          // conv1 pos-half: {0,1,2} or {3,4}
    const int NT  = nh ? 2 : 3;

    for (int it = tid; it < 96; it += 256) {
        char* p;
        if (it < 32)       p = smem + it * 8;
        else if (it < 64)  p = smem + 81 * 256 + (it - 32) * 8;
        else if (it < 80)  p = smem + X1_OFF + (it - 64) * 8;
        else               p = smem + X1_OFF + 81 * 128 + (it - 80) * 8;
        *(uint2*)p = make_uint2(0u, 0u);
    }
    {
        const int g = tid >> 5, c4 = tid & 31;
        const int sbase = (((1 + g) * 256 + c4 * 8) ^ SWZ(1 + g));
        const int posb = l0 - 8 + g;
        int tok[10];
        #pragma unroll
        for (int it = 0; it < 10; ++it) {
            const int pos = posb + it * 8;
            tok[it] = (pos >= 0 && pos < Ls) ? text[b * Ls + pos] : -1;
        }
        float4 ev[10];
        #pragma unroll
        for (int it = 0; it < 10; ++it)
            ev[it] = (tok[it] >= 0) ? ((const float4*)embed)[tok[it] * 32 + c4]
                                    : make_float4(0.f, 0.f, 0.f, 0.f);
        #pragma unroll
        for (int it = 0; it < 10; ++it) {
            uint2 val;
            val.x = pk2bf(ev[it].x, ev[it].y);
            val.y = pk2bf(ev[it].z, ev[it].w);
            const int addr = (sbase + it * 2048) ^ ((it & 1) << 5);
            *(uint2*)(smem + addr) = val;
        }
    }
    __syncthreads();

    // ---- conv1 (pos-split): wave = chans {2mh,2mh+1} x NT pos-tiles, K=3x128
    // per-t batched 8-frag wf prefetch (R8 fix for R7's exposed L2 latency)
    {
        const float4 bz0 = *(const float4*)(b1 + (2 * mh) * 16 + kg * 4);
        const float4 bz1 = *(const float4*)(b1 + (2 * mh + 1) * 16 + kg * 4);
        f32x4 acc[2][3];
        #pragma unroll
        for (int n = 0; n < 3; ++n) {
            acc[0][n][0]=bz0.x; acc[0][n][1]=bz0.y; acc[0][n][2]=bz0.z; acc[0][n][3]=bz0.w;
            acc[1][n][0]=bz1.x; acc[1][n][1]=bz1.y; acc[1][n][2]=bz1.z; acc[1][n][3]=bz1.w;
        }
        #pragma unroll
        for (int t = 0; t < 3; ++t) {
            s16x8 wf[8];                    // [kc*2 + m]
            #pragma unroll
            for (int kc = 0; kc < 4; ++kc) {
                wf[kc * 2]     = *(const s16x8*)(wfrag + ((t * 4 + kc) * 4 + 2 * mh)     * 64 + lane);
                wf[kc * 2 + 1] = *(const s16x8*)(wfrag + ((t * 4 + kc) * 4 + 2 * mh + 1) * 64 + lane);
            }
            __builtin_amdgcn_sched_barrier(0);
            #pragma unroll
            for (int kc = 0; kc < 4; ++kc) {
                const int xb = (((nl + t) * 256 + kc * 64 + kg * 16) ^ SWZ(nl + t)) + nt0 * 4096;
                #pragma unroll
                for (int n = 0; n < 3; ++n) {
                    if (n < NT) {
                        const s16x8 a = *(const s16x8*)(smem + xb + n * 4096);
                        acc[0][n] = __builtin_amdgcn_mfma_f32_16x16x32_bf16(wf[kc * 2],     a, acc[0][n], 0, 0, 0);
                        acc[1][n] = __builtin_amdgcn_mfma_f32_16x16x32_bf16(wf[kc * 2 + 1], a, acc[1][n], 0, 0, 0);
                    }
                }
            }
        }
        #pragma unroll
        for (int n = 0; n < 3; ++n) {
            if (n < NT) {
                const int pos = l0 - 8 + (nt0 + n) * 16 + nl;
                const bool ok = (pos >= 0) && (pos < Ls);
                #pragma unroll
                for (int m = 0; m < 2; ++m) {
                    const int wbx = (X1_OFF + (nl + 1) * 128 + ((2 * mh + m) * 16 + kg * 4) * 2) ^ SWZ(nl + 1);
                    uint2 pk;
                    pk.x = ok ? pk2bf(fmaxf(acc[m][n][0], 0.f), fmaxf(acc[m][n][1], 0.f)) : 0u;
                    pk.y = ok ? pk2bf(fmaxf(acc[m][n][2], 0.f), fmaxf(acc[m][n][3], 0.f)) : 0u;
                    *(uint2*)(smem + wbx + (nt0 + n) * 2048) = pk;
                }
            }
        }
    }
    __syncthreads();

    // ---- conv2: wave = chans {wv,wv+4} x 5 pos-tiles, K=3x64  (R8/R12)
    {
        const float4 bz0 = *(const float4*)(b2 + wv * 16 + kg * 4);
        const float4 bz1 = *(const float4*)(b2 + (wv + 4) * 16 + kg * 4);
        s16x8 wf[12];
        #pragma unroll
        for (int i = 0; i < 6; ++i) {
            wf[2 * i]     = *(const s16x8*)(wfrag + (48 + i * 8 + wv) * 64 + lane);
            wf[2 * i + 1] = *(const s16x8*)(wfrag + (48 + i * 8 + wv + 4) * 64 + lane);
        }
        __builtin_amdgcn_sched_barrier(0);
        f32x4 acc0[5], acc1[5];
        #pragma unroll
        for (int n = 0; n < 5; ++n) {
            acc0[n][0]=bz0.x; acc0[n][1]=bz0.y; acc0[n][2]=bz0.z; acc0[n][3]=bz0.w;
            acc1[n][0]=bz1.x; acc1[n][1]=bz1.y; acc1[n][2]=bz1.z; acc1[n][3]=bz1.w;
        }
        #pragma unroll
        for (int t = 0; t < 3; ++t) {
            #pragma unroll
            for (int kc = 0; kc < 2; ++kc) {
                const int xb = ((X1_OFF + (nl + t) * 128 + kc * 64 + kg * 16) ^ SWZ(nl + t));
                const int i = t * 2 + kc;
                #pragma unroll
                for (int n = 0; n < 5; ++n) {
                    const s16x8 a = *(const s16x8*)(smem + xb + n * 2048);
                    acc0[n] = __builtin_amdgcn_mfma_f32_16x16x32_bf16(wf[2 * i],     a, acc0[n], 0, 0, 0);
                    acc1[n] = __builtin_amdgcn_mfma_f32_16x16x32_bf16(wf[2 * i + 1], a, acc1[n], 0, 0, 0);
                }
            }
        }
        const int wb0 = (nl * 256 + (wv * 16 + kg * 4) * 2) ^ SWZ(nl);
        const int wb1 = (nl * 256 + ((wv + 4) * 16 + kg * 4) * 2) ^ SWZ(nl);
        #pragma unroll
        for (int n = 0; n < 5; ++n) {
            const int pos = l0 - 8 + n * 16 + nl;
            const bool ok = (pos >= 0) && (pos < Ls);
            uint2 pa, pb;
            pa.x = ok ? pk2bf(fmaxf(acc0[n][0], 0.f), fmaxf(acc0[n][1], 0.f)) : 0u;
            pa.y = ok ? pk2bf(fmaxf(acc0[n][2], 0.f), fmaxf(acc0[n][3], 0.f)) : 0u;
            pb.x = ok ? pk2bf(fmaxf(acc1[n][0], 0.f), fmaxf(acc1[n][1], 0.f)) : 0u;
            pb.y = ok ? pk2bf(fmaxf(acc1[n][2], 0.f), fmaxf(acc1[n][3], 0.f)) : 0u;
            *(uint2*)(smem + wb0 + n * 4096) = pa;
            *(uint2*)(smem + wb1 + n * 4096) = pb;
        }
    }
    __syncthreads();

    // ---- conv3 (dil 2): wave = chans {wv,wv+4} x 4 pos-tiles, K=3x128  (R8/R12)
    {
        const float4 bz0 = *(const float4*)(b3 + wv * 16 + kg * 4);
        const float4 bz1 = *(const float4*)(b3 + (wv + 4) * 16 + kg * 4);
        f32x4 acc0[4], acc1[4];
        #pragma unroll
        for (int n = 0; n < 4; ++n) {
            acc0[n][0]=bz0.x; acc0[n][1]=bz0.y; acc0[n][2]=bz0.z; acc0[n][3]=bz0.w;
            acc1[n][0]=bz1.x; acc1[n][1]=bz1.y; acc1[n][2]=bz1.z; acc1[n][3]=bz1.w;
        }
        #pragma unroll
        for (int half = 0; half < 2; ++half) {
            s16x8 wf[12];
            #pragma unroll
            for (int t = 0; t < 3; ++t)
                #pragma unroll
                for (int kh = 0; kh < 2; ++kh) {
                    const int fi = 96 + (t * 4 + 2 * half + kh) * 8;
                    wf[(t * 2 + kh) * 2]     = *(const s16x8*)(wfrag + (fi + wv) * 64 + lane);
                    wf[(t * 2 + kh) * 2 + 1] = *(const s16x8*)(wfrag + (fi + wv + 4) * 64 + lane);
                }
            __builtin_amdgcn_sched_barrier(0);
            #pragma unroll
            for (int t = 0; t < 3; ++t) {
                #pragma unroll
                for (int kh = 0; kh < 2; ++kh) {
                    const int q = nl + 6 + 2 * t;
                    const int xb = ((q * 256 + (2 * half + kh) * 64 + kg * 16) ^ SWZ(q));
                    const int i = t * 2 + kh;
                    #pragma unroll
                    for (int n = 0; n < 4; ++n) {
                        const s16x8 a = *(const s16x8*)(smem + xb + n * 4096);
                        acc0[n] = __builtin_amdgcn_mfma_f32_16x16x32_bf16(wf[2 * i],     a, acc0[n], 0, 0, 0);
                        acc1[n] = __builtin_amdgcn_mfma_f32_16x16x32_bf16(wf[2 * i + 1], a, acc1[n], 0, 0, 0);
                    }
                }
            }
        }
        const int wb0 = (X3_OFF + nl * 256 + (wv * 16 + kg * 4) * 2) ^ SWZ(nl);
        const int wb1 = (X3_OFF + nl * 256 + ((wv + 4) * 16 + kg * 4) * 2) ^ SWZ(nl);
        #pragma unroll
        for (int n = 0; n < 4; ++n) {
            uint2 pa, pb;
            pa.x = pk2bf(fmaxf(acc0[n][0], 0.f), fmaxf(acc0[n][1], 0.f));
            pa.y = pk2bf(fmaxf(acc0[n][2], 0.f), fmaxf(acc0[n][3], 0.f));
            pb.x = pk2bf(fmaxf(acc1[n][0], 0.f), fmaxf(acc1[n][1], 0.f));
            pb.y = pk2bf(fmaxf(acc1[n][2], 0.f), fmaxf(acc1[n][3], 0.f));
            *(uint2*)(smem + wb0 + n * 4096) = pa;
            *(uint2*)(smem + wb1 + n * 4096) = pb;
        }
    }
    __syncthreads();

    // ---- dense 128 -> 9 via MFMA
    {
        s16x8 dwf[4];
        #pragma unroll
        for (int kc = 0; kc < 4; ++kc)
            dwf[kc] = *(const s16x8*)(wfrag + (192 + kc) * 64 + lane);
        __builtin_amdgcn_sched_barrier(0);
        const float bdv = (nl < Kk) ? bd[nl] : 0.f;
        f32x4 dacc;
        dacc[0] = bdv; dacc[1] = bdv; dacc[2] = bdv; dacc[3] = bdv;
        #pragma unroll
        for (int kc = 0; kc < 4; ++kc) {
            const int ad = (X3_OFF + (wv * 16 + nl) * 256 + kc * 64 + kg * 16) ^ SWZ(nl);
            const s16x8 a = *(const s16x8*)(smem + ad);
            dacc = __builtin_amdgcn_mfma_f32_16x16x32_bf16(a, dwf[kc], dacc, 0, 0, 0);
        }
        if (nl < Kk) {
            #pragma unroll
            for (int r = 0; r < 4; ++r) {
                const int p = wv * 16 + kg * 4 + r;
                logits[((size_t)b * Ls + l0 + p) * Kk + nl] = dacc[r];
            }
        }
    }
}

// ---- CRF fused: chunked forward (waves 0-3) + lens/score (wave 4) + combine.
#define MN63(x) (((x) < 63) ? (x) : 63)
#define RDLV(v, i) __int_as_float(__builtin_amdgcn_readlane(__float_as_int(v), (i)))

#define GSTEP(LG, s) { \
    const int t_ = base + (s); \
    const float e_ = __expf(LG); \
    float p0 = __shfl(f, gb + 0) * tc[0]; \
    float p1 = __shfl(f, gb + 1) * tc[1]; \
    float p2 = __shfl(f, gb + 2) * tc[2]; \
    float p3 = __shfl(f, gb + 3) * tc[3]; \
    float p4 = __shfl(f, gb + 4) * tc[4]; \
    float p5 = __shfl(f, gb + 5) * tc[5]; \
    float p6 = __shfl(f, gb + 6) * tc[6]; \
    float p7 = __shfl(f, gb + 7) * tc[7]; \
    float p8 = __shfl(f, gb + 8) * tc[8]; \
    const float s_ = ((p0 + p1) + (p2 + p3)) + ((p4 + p5) + (p6 + p7)) + p8; \
    const float nf_ = e_ * s_; \
    f = (t_ >= 1 && t_ < len) ? nf_ : f; }

#define GRN() { \
    const float mb_ = __shfl(f, gb); \
    const float mm_ = rn_ok ? fmaxf(mb_, 1e-30f) : 1.0f; \
    C += __logf(mm_); \
    f *= (1.0f / mm_); }

__global__ __launch_bounds__(320) void kc_fused(
    const int* __restrict__ text, const int* __restrict__ labels,
    const float* __restrict__ trans, const float* __restrict__ logits,
    float* __restrict__ lens_out, float* __restrict__ ll_out)
{
    const int row = blockIdx.x;
    const int tid = threadIdx.x;
    const int lane = tid & 63, w = tid >> 6;
    __shared__ float trS[81];
    __shared__ int lenS;
    __shared__ float scoreS;
    __shared__ float fS[28][12];
    for (int i = tid; i < 81; i += 320) trS[i] = trans[i];

    if (w == 4) {
        const int4 tx = ((const int4*)(text + (size_t)row * Ls))[lane];
        int c = (tx.x != 0) + (tx.y != 0) + (tx.z != 0) + (tx.w != 0);
        #pragma unroll
        for (int off = 1; off < 64; off <<= 1) c += __shfl_xor(c, off);
        if (lane == 0) { lenS = c; lens_out[row] = (float)c; }
    }
    __syncthreads();
    const int len = lenS;

    if (w < 4) {
        const int graw = lane / 9;
        const bool act = (graw < 7);
        const int g  = act ? graw : 6;
        const int gb = g * 9;
        const int ig = (lane - gb < 9) ? (lane - gb) : 8;
        const int task  = w * 7 + g;
        const int chunk = (task == 0) ? 0 : 1 + (task - 1) / 9;
        const int colj  = (task == 0) ? 0 : (task - 1) % 9;
        const int base  = chunk * 64;
        const bool rn_ok = (task == 0) || (base < len);

        float tc[9];
        #pragma unroll
        for (int k = 0; k < 9; ++k) tc[k] = __expf(trS[k * 9 + ig]);

        const float* lp = logits + (size_t)row * Ls * Kk + base * Kk + ig;
        float f = (task == 0) ? __expf(lp[0]) : ((ig == colj) ? 1.f : 0.f);
        float C = 0.f;

        float a0 = lp[0],      a1 = lp[9 * 1],  a2 = lp[9 * 2],  a3 = lp[9 * 3];
        float a4 = lp[9 * 4],  a5 = lp[9 * 5],  a6 = lp[9 * 6],  a7 = lp[9 * 7];

        #pragma unroll 1
        for (int kk = 0; kk < 8; ++kk) {
            const int nb = 8 * kk + 8;
            const float b0 = lp[9 * MN63(nb + 0)], b1 = lp[9 * MN63(nb + 1)];
            const float b2 = lp[9 * MN63(nb + 2)], b3 = lp[9 * MN63(nb + 3)];
            const float b4 = lp[9 * MN63(nb + 4)], b5 = lp[9 * MN63(nb + 5)];
            const float b6 = lp[9 * MN63(nb + 6)], b7 = lp[9 * MN63(nb + 7)];
            const int sb = 8 * kk;
            GSTEP(a0, sb + 0) GSTEP(a1, sb + 1) GSTEP(a2, sb + 2) GSTEP(a3, sb + 3)
            GSTEP(a4, sb + 4) GSTEP(a5, sb + 5) GSTEP(a6, sb + 6) GSTEP(a7, sb + 7)
            GRN()
            a0 = b0; a1 = b1; a2 = b2; a3 = b3;
            a4 = b4; a5 = b5; a6 = b6; a7 = b7;
        }

        if (act) {
            fS[task][ig] = f;
            if (ig == 0) fS[task][9] = C;
        }
    } else {
        const int4 lb = ((const int4*)(labels + (size_t)row * Ls))[lane];
        const int t0 = lane * 4;
        int la[5];
        la[0] = lb.x; la[1] = lb.y; la[2] = lb.z; la[3] = lb.w;
        la[4] = (t0 + 4 < Ls) ? labels[(size_t)row * Ls + t0 + 4] : 0;
        const float* lgrow = logits + (size_t)row * Ls * Kk;
        float sc = 0.f;
        #pragma unroll
        for (int q = 0; q < 4; ++q) {
            const int t = t0 + q;
            if (t < len) sc += lgrow[t * Kk + la[q]];
            if (t < len - 1) sc += trS[la[q] * Kk + la[q + 1]];
        }
        #pragma unroll
        for (int off = 1; off < 64; off <<= 1) sc += __shfl_xor(sc, off);
        if (lane == 0) scoreS = sc;
    }
    __syncthreads();

    if (w == 0) {
        const int i9 = (lane < 9) ? lane : 0;
        float v = (lane < 9) ? fS[0][lane] : 0.f;
        float Ct = fS[0][9];

        #pragma unroll
        for (int cc = 1; cc <= 3; ++cc) {
            const int tb = 1 + 9 * (cc - 1);
            float Cc[9];
            #pragma unroll
            for (int j = 0; j < 9; ++j) Cc[j] = fS[tb + j][9];
            float Cm = Cc[0];
            #pragma unroll
            for (int j = 1; j < 9; ++j) Cm = fmaxf(Cm, Cc[j]);
            const float u0 = RDLV(v, 0), u1 = RDLV(v, 1), u2 = RDLV(v, 2);
            const float u3 = RDLV(v, 3), u4 = RDLV(v, 4), u5 = RDLV(v, 5);
            const float u6 = RDLV(v, 6), u7 = RDLV(v, 7), u8 = RDLV(v, 8);
            float vo = 0.f;
            vo = fmaf(fS[tb + 0][i9], __expf(Cc[0] - Cm) * u0, vo);
            vo = fmaf(fS[tb + 1][i9], __expf(Cc[1] - Cm) * u1, vo);
            vo = fmaf(fS[tb + 2][i9], __expf(Cc[2] - Cm) * u2, vo);
            vo = fmaf(fS[tb + 3][i9], __expf(Cc[3] - Cm) * u3, vo);
            vo = fmaf(fS[tb + 4][i9], __expf(Cc[4] - Cm) * u4, vo);
            vo = fmaf(fS[tb + 5][i9], __expf(Cc[5] - Cm) * u5, vo);
            vo = fmaf(fS[tb + 6][i9], __expf(Cc[6] - Cm) * u6, vo);
            vo = fmaf(fS[tb + 7][i9], __expf(Cc[7] - Cm) * u7, vo);
            vo = fmaf(fS[tb + 8][i9], __expf(Cc[8] - Cm) * u8, vo);
            v = (lane < 9) ? vo : 0.f;
            Ct += Cm;
        }

        float sum = v;
        sum += __shfl_xor(sum, 1, 16);
        sum += __shfl_xor(sum, 2, 16);
        sum += __shfl_xor(sum, 4, 16);
        sum += __shfl_xor(sum, 8, 16);
        if (lane == 0) ll_out[row] = scoreS - (Ct + __logf(sum));
    }
}

extern "C" void kernel_launch(void* const* d_in, const int* in_sizes, int n_in,
                              void* d_out, int out_size, void* d_ws, size_t ws_size,
                              hipStream_t stream) {
    const int*   text   = (const int*)d_in[0];
    const int*   labels = (const int*)d_in[1];
    const float* embed  = (const float*)d_in[2];
    const float* w1 = (const float*)d_in[3];
    const float* b1 = (const float*)d_in[4];
    const float* w2 = (const float*)d_in[5];
    const float* b2 = (const float*)d_in[6];
    const float* w3 = (const float*)d_in[7];
    const float* b3 = (const float*)d_in[8];
    const float* wd = (const float*)d_in[9];
    const float* bd = (const float*)d_in[10];
    const float* trans = (const float*)d_in[11];

    float* out      = (float*)d_out;
    float* logits   = out;
    float* lens_out = out + (size_t)Bb * Ls * Kk;
    float* ll_out   = lens_out + Bb;
    uint4* wfrag    = (uint4*)d_ws;     // 196 KiB

    hipLaunchKernelGGL(kw_prep, dim3(49), dim3(256), 0, stream, w1, w2, w3, wd, wfrag);
    hipLaunchKernelGGL(kmain, dim3(Ls / 64, Bb), dim3(256), 0, stream,
                       text, embed, wfrag, b1, b2, b3, bd, logits);
    hipLaunchKernelGGL(kc_fused, dim3(Bb), dim3(320), 0, stream,
                       text, labels, trans, logits, lens_out, ll_out);
}

// Round 14
// 63.441 us; speedup vs baseline: 1.0123x; 1.0123x over previous
//
#include <hip/hip_runtime.h>
#include <hip/hip_bf16.h>

#define Ls 256
#define Kk 9
#define Bb 512

typedef short s16x8 __attribute__((ext_vector_type(8)));
typedef float f32x4 __attribute__((ext_vector_type(4)));

__device__ __forceinline__ unsigned short f2bf(float f) {
    __hip_bfloat16 h = __float2bfloat16(f);
    return *reinterpret_cast<unsigned short*>(&h);
}
__device__ __forceinline__ unsigned pk2bf(float a, float b) {
    __hip_bfloat162 h = __float22bfloat162_rn(make_float2(a, b));
    return *reinterpret_cast<unsigned*>(&h);
}

// XOR swizzle on byte addr bits 4-6, function of row&15 only.
#define SWZ(row) (((((row)&7)<<4)) ^ ((((row)&8))<<2))

// ---- weight prep: pack w1/w2/w3/wd into bf16 MFMA fragments ----
__global__ __launch_bounds__(256) void kw_prep(
    const float* __restrict__ w1, const float* __restrict__ w2, const float* __restrict__ w3,
    const float* __restrict__ wd, uint4* __restrict__ wfrag)
{
    const int gid = blockIdx.x * 256 + threadIdx.x;
    const int frag = gid >> 6;
    const int lane = gid & 63;
    if (frag >= 196) return;
    const int kb = (lane >> 4) * 8;
    const int nl = lane & 15;
    float v[8];
    if (frag < 48) {
        int nt = frag & 3, kc = (frag >> 2) & 3, t = frag >> 4;
        int n = nt * 16 + nl;
        #pragma unroll
        for (int j = 0; j < 8; ++j) v[j] = w1[(t * 128 + kc * 32 + kb + j) * 64 + n];
    } else if (frag < 96) {
        int f = frag - 48; int nt = f & 7, kc = (f >> 3) & 1, t = f >> 4;
        int n = nt * 16 + nl;
        #pragma unroll
        for (int j = 0; j < 8; ++j) v[j] = w2[(t * 64 + kc * 32 + kb + j) * 128 + n];
    } else if (frag < 192) {
        int f = frag - 96; int nt = f & 7, kc = (f >> 3) & 3, t = f >> 5;
        int n = nt * 16 + nl;
        #pragma unroll
        for (int j = 0; j < 8; ++j) v[j] = w3[(t * 128 + kc * 32 + kb + j) * 128 + n];
    } else {
        int kc = frag - 192;
        #pragma unroll
        for (int j = 0; j < 8; ++j) v[j] = (nl < Kk) ? wd[(kc * 32 + kb + j) * Kk + nl] : 0.f;
    }
    uint4 o;
    o.x = (unsigned)f2bf(v[0]) | ((unsigned)f2bf(v[1]) << 16);
    o.y = (unsigned)f2bf(v[2]) | ((unsigned)f2bf(v[3]) << 16);
    o.z = (unsigned)f2bf(v[4]) | ((unsigned)f2bf(v[5]) << 16);
    o.w = (unsigned)f2bf(v[6]) | ((unsigned)f2bf(v[7]) << 16);
    wfrag[frag * 64 + lane] = o;
}

// ---- fused embed + conv1 + conv2 + conv3(dil2) + dense(MFMA) ----  (R12 best)
#define X1_OFF  20992
#define X3_OFF  20992
#define SMEM_BYTES (20992 + 64 * 256)   // 37376 -> 4 blocks/CU

__global__ __launch_bounds__(256, 4) void kmain(
    const int* __restrict__ text, const float* __restrict__ embed,
    const uint4* __restrict__ wfrag,
    const float* __restrict__ b1, const float* __restrict__ b2, const float* __restrict__ b3,
    const float* __restrict__ bd,
    float* __restrict__ logits)
{
    __shared__ __align__(16) char smem[SMEM_BYTES];
    const int b = blockIdx.y, l0 = blockIdx.x * 64;
    const int tid = threadIdx.x;
    const int lane = tid & 63, wv = tid >> 6;
    const int nl = lane & 15, kg = lane >> 4;

    for (int it = tid; it < 96; it += 256) {
        char* p;
        if (it < 32)       p = smem + it * 8;
        else if (it < 64)  p = smem + 81 * 256 + (it - 32) * 8;
        else if (it < 80)  p = smem + X1_OFF + (it - 64) * 8;
        else               p = smem + X1_OFF + 81 * 128 + (it - 80) * 8;
        *(uint2*)p = make_uint2(0u, 0u);
    }
    {
        const int g = tid >> 5, c4 = tid & 31;
        const int sbase = (((1 + g) * 256 + c4 * 8) ^ SWZ(1 + g));
        const int posb = l0 - 8 + g;
        int tok[10];
        #pragma unroll
        for (int it = 0; it < 10; ++it) {
            const int pos = posb + it * 8;
            tok[it] = (pos >= 0 && pos < Ls) ? text[b * Ls + pos] : -1;
        }
        float4 ev[10];
        #pragma unroll
        for (int it = 0; it < 10; ++it)
            ev[it] = (tok[it] >= 0) ? ((const float4*)embed)[tok[it] * 32 + c4]
                                    : make_float4(0.f, 0.f, 0.f, 0.f);
        #pragma unroll
        for (int it = 0; it < 10; ++it) {
            uint2 val;
            val.x = pk2bf(ev[it].x, ev[it].y);
            val.y = pk2bf(ev[it].z, ev[it].w);
            const int addr = (sbase + it * 2048) ^ ((it & 1) << 5);
            *(uint2*)(smem + addr) = val;
        }
    }
    __syncthreads();

    // ---- conv1: wave = chan-tile wv x 5 pos-tiles, K=3x128
    {
        const float4 bz = *(const float4*)(b1 + wv * 16 + kg * 4);
        s16x8 wf[12];
        #pragma unroll
        for (int i = 0; i < 12; ++i)
            wf[i] = *(const s16x8*)(wfrag + (i * 4 + wv) * 64 + lane);
        __builtin_amdgcn_sched_barrier(0);
        f32x4 acc[5];
        #pragma unroll
        for (int n = 0; n < 5; ++n) { acc[n][0]=bz.x; acc[n][1]=bz.y; acc[n][2]=bz.z; acc[n][3]=bz.w; }
        #pragma unroll
        for (int t = 0; t < 3; ++t) {
            #pragma unroll
            for (int kc = 0; kc < 4; ++kc) {
                const int xb = (((nl + t) * 256 + kc * 64 + kg * 16) ^ SWZ(nl + t));
                #pragma unroll
                for (int n = 0; n < 5; ++n) {
                    const s16x8 a = *(const s16x8*)(smem + xb + n * 4096);
                    acc[n] = __builtin_amdgcn_mfma_f32_16x16x32_bf16(wf[t * 4 + kc], a, acc[n], 0, 0, 0);
                }
            }
        }
        const int wb = (X1_OFF + (nl + 1) * 128 + (wv * 16 + kg * 4) * 2) ^ SWZ(nl + 1);
        #pragma unroll
        for (int n = 0; n < 5; ++n) {
            const int pos = l0 - 8 + n * 16 + nl;
            const bool ok = (pos >= 0) && (pos < Ls);
            uint2 pk;
            pk.x = ok ? pk2bf(fmaxf(acc[n][0], 0.f), fmaxf(acc[n][1], 0.f)) : 0u;
            pk.y = ok ? pk2bf(fmaxf(acc[n][2], 0.f), fmaxf(acc[n][3], 0.f)) : 0u;
            *(uint2*)(smem + wb + n * 2048) = pk;
        }
    }
    __syncthreads();

    // ---- conv2: wave = chans {wv,wv+4} x 5 pos-tiles, K=3x64
    {
        const float4 bz0 = *(const float4*)(b2 + wv * 16 + kg * 4);
        const float4 bz1 = *(const float4*)(b2 + (wv + 4) * 16 + kg * 4);
        s16x8 wf[12];
        #pragma unroll
        for (int i = 0; i < 6; ++i) {
            wf[2 * i]     = *(const s16x8*)(wfrag + (48 + i * 8 + wv) * 64 + lane);
            wf[2 * i + 1] = *(const s16x8*)(wfrag + (48 + i * 8 + wv + 4) * 64 + lane);
        }
        __builtin_amdgcn_sched_barrier(0);
        f32x4 acc0[5], acc1[5];
        #pragma unroll
        for (int n = 0; n < 5; ++n) {
            acc0[n][0]=bz0.x; acc0[n][1]=bz0.y; acc0[n][2]=bz0.z; acc0[n][3]=bz0.w;
            acc1[n][0]=bz1.x; acc1[n][1]=bz1.y; acc1[n][2]=bz1.z; acc1[n][3]=bz1.w;
        }
        #pragma unroll
        for (int t = 0; t < 3; ++t) {
            #pragma unroll
            for (int kc = 0; kc < 2; ++kc) {
                const int xb = ((X1_OFF + (nl + t) * 128 + kc * 64 + kg * 16) ^ SWZ(nl + t));
                const int i = t * 2 + kc;
                #pragma unroll
                for (int n = 0; n < 5; ++n) {
                    const s16x8 a = *(const s16x8*)(smem + xb + n * 2048);
                    acc0[n] = __builtin_amdgcn_mfma_f32_16x16x32_bf16(wf[2 * i],     a, acc0[n], 0, 0, 0);
                    acc1[n] = __builtin_amdgcn_mfma_f32_16x16x32_bf16(wf[2 * i + 1], a, acc1[n], 0, 0, 0);
                }
            }
        }
        const int wb0 = (nl * 256 + (wv * 16 + kg * 4) * 2) ^ SWZ(nl);
        const int wb1 = (nl * 256 + ((wv + 4) * 16 + kg * 4) * 2) ^ SWZ(nl);
        #pragma unroll
        for (int n = 0; n < 5; ++n) {
            const int pos = l0 - 8 + n * 16 + nl;
            const bool ok = (pos >= 0) && (pos < Ls);
            uint2 pa, pb;
            pa.x = ok ? pk2bf(fmaxf(acc0[n][0], 0.f), fmaxf(acc0[n][1], 0.f)) : 0u;
            pa.y = ok ? pk2bf(fmaxf(acc0[n][2], 0.f), fmaxf(acc0[n][3], 0.f)) : 0u;
            pb.x = ok ? pk2bf(fmaxf(acc1[n][0], 0.f), fmaxf(acc1[n][1], 0.f)) : 0u;
            pb.y = ok ? pk2bf(fmaxf(acc1[n][2], 0.f), fmaxf(acc1[n][3], 0.f)) : 0u;
            *(uint2*)(smem + wb0 + n * 4096) = pa;
            *(uint2*)(smem + wb1 + n * 4096) = pb;
        }
    }
    __syncthreads();

    // ---- conv3 (dil 2): wave = chans {wv,wv+4} x 4 pos-tiles, K=3x128
    {
        const float4 bz0 = *(const float4*)(b3 + wv * 16 + kg * 4);
        const float4 bz1 = *(const float4*)(b3 + (wv + 4) * 16 + kg * 4);
        f32x4 acc0[4], acc1[4];
        #pragma unroll
        for (int n = 0; n < 4; ++n) {
            acc0[n][0]=bz0.x; acc0[n][1]=bz0.y; acc0[n][2]=bz0.z; acc0[n][3]=bz0.w;
            acc1[n][0]=bz1.x; acc1[n][1]=bz1.y; acc1[n][2]=bz1.z; acc1[n][3]=bz1.w;
        }
        #pragma unroll
        for (int half = 0; half < 2; ++half) {
            s16x8 wf[12];
            #pragma unroll
            for (int t = 0; t < 3; ++t)
                #pragma unroll
                for (int kh = 0; kh < 2; ++kh) {
                    const int fi = 96 + (t * 4 + 2 * half + kh) * 8;
                    wf[(t * 2 + kh) * 2]     = *(const s16x8*)(wfrag + (fi + wv) * 64 + lane);
                    wf[(t * 2 + kh) * 2 + 1] = *(const s16x8*)(wfrag + (fi + wv + 4) * 64 + lane);
                }
            __builtin_amdgcn_sched_barrier(0);
            #pragma unroll
            for (int t = 0; t < 3; ++t) {
                #pragma unroll
                for (int kh = 0; kh < 2; ++kh) {
                    const int q = nl + 6 + 2 * t;
                    const int xb = ((q * 256 + (2 * half + kh) * 64 + kg * 16) ^ SWZ(q));
                    const int i = t * 2 + kh;
                    #pragma unroll
                    for (int n = 0; n < 4; ++n) {
                        const s16x8 a = *(const s16x8*)(smem + xb + n * 4096);
                        acc0[n] = __builtin_amdgcn_mfma_f32_16x16x32_bf16(wf[2 * i],     a, acc0[n], 0, 0, 0);
                        acc1[n] = __builtin_amdgcn_mfma_f32_16x16x32_bf16(wf[2 * i + 1], a, acc1[n], 0, 0, 0);
                    }
                }
            }
        }
        const int wb0 = (X3_OFF + nl * 256 + (wv * 16 + kg * 4) * 2) ^ SWZ(nl);
        const int wb1 = (X3_OFF + nl * 256 + ((wv + 4) * 16 + kg * 4) * 2) ^ SWZ(nl);
        #pragma unroll
        for (int n = 0; n < 4; ++n) {
            uint2 pa, pb;
            pa.x = pk2bf(fmaxf(acc0[n][0], 0.f), fmaxf(acc0[n][1], 0.f));
            pa.y = pk2bf(fmaxf(acc0[n][2], 0.f), fmaxf(acc0[n][3], 0.f));
            pb.x = pk2bf(fmaxf(acc1[n][0], 0.f), fmaxf(acc1[n][1], 0.f));
            pb.y = pk2bf(fmaxf(acc1[n][2], 0.f), fmaxf(acc1[n][3], 0.f));
            *(uint2*)(smem + wb0 + n * 4096) = pa;
            *(uint2*)(smem + wb1 + n * 4096) = pb;
        }
    }
    __syncthreads();

    // ---- dense 128 -> 9 via MFMA
    {
        s16x8 dwf[4];
        #pragma unroll
        for (int kc = 0; kc < 4; ++kc)
            dwf[kc] = *(const s16x8*)(wfrag + (192 + kc) * 64 + lane);
        __builtin_amdgcn_sched_barrier(0);
        const float bdv = (nl < Kk) ? bd[nl] : 0.f;
        f32x4 dacc;
        dacc[0] = bdv; dacc[1] = bdv; dacc[2] = bdv; dacc[3] = bdv;
        #pragma unroll
        for (int kc = 0; kc < 4; ++kc) {
            const int ad = (X3_OFF + (wv * 16 + nl) * 256 + kc * 64 + kg * 16) ^ SWZ(nl);
            const s16x8 a = *(const s16x8*)(smem + ad);
            dacc = __builtin_amdgcn_mfma_f32_16x16x32_bf16(a, dwf[kc], dacc, 0, 0, 0);
        }
        if (nl < Kk) {
            #pragma unroll
            for (int r = 0; r < 4; ++r) {
                const int p = wv * 16 + kg * 4 + r;
                logits[((size_t)b * Ls + l0 + p) * Kk + nl] = dacc[r];
            }
        }
    }
}

// ---- CRF fused: chunked forward (waves 0-3) + lens/score (wave 4) + combine.
#define MN63(x) (((x) < 63) ? (x) : 63)
#define RDLV(v, i) __int_as_float(__builtin_amdgcn_readlane(__float_as_int(v), (i)))

#define GSTEP(LG, s) { \
    const int t_ = base + (s); \
    const float e_ = __expf(LG); \
    float p0 = __shfl(f, gb + 0) * tc[0]; \
    float p1 = __shfl(f, gb + 1) * tc[1]; \
    float p2 = __shfl(f, gb + 2) * tc[2]; \
    float p3 = __shfl(f, gb + 3) * tc[3]; \
    float p4 = __shfl(f, gb + 4) * tc[4]; \
    float p5 = __shfl(f, gb + 5) * tc[5]; \
    float p6 = __shfl(f, gb + 6) * tc[6]; \
    float p7 = __shfl(f, gb + 7) * tc[7]; \
    float p8 = __shfl(f, gb + 8) * tc[8]; \
    const float s_ = ((p0 + p1) + (p2 + p3)) + ((p4 + p5) + (p6 + p7)) + p8; \
    const float nf_ = e_ * s_; \
    f = (t_ >= 1 && t_ < len) ? nf_ : f; }

#define GRN() { \
    const float mb_ = __shfl(f, gb); \
    const float mm_ = rn_ok ? fmaxf(mb_, 1e-30f) : 1.0f; \
    C += __logf(mm_); \
    f *= (1.0f / mm_); }

__global__ __launch_bounds__(320) void kc_fused(
    const int* __restrict__ text, const int* __restrict__ labels,
    const float* __restrict__ trans, const float* __restrict__ logits,
    float* __restrict__ lens_out, float* __restrict__ ll_out)
{
    const int row = blockIdx.x;
    const int tid = threadIdx.x;
    const int lane = tid & 63, w = tid >> 6;
    __shared__ float trS[81];
    __shared__ int lenS;
    __shared__ float scoreS;
    __shared__ float fS[28][12];
    for (int i = tid; i < 81; i += 320) trS[i] = trans[i];

    if (w == 4) {
        const int4 tx = ((const int4*)(text + (size_t)row * Ls))[lane];
        int c = (tx.x != 0) + (tx.y != 0) + (tx.z != 0) + (tx.w != 0);
        #pragma unroll
        for (int off = 1; off < 64; off <<= 1) c += __shfl_xor(c, off);
        if (lane == 0) { lenS = c; lens_out[row] = (float)c; }
    }
    __syncthreads();
    const int len = lenS;

    if (w < 4) {
        const int graw = lane / 9;
        const bool act = (graw < 7);
        const int g  = act ? graw : 6;
        const int gb = g * 9;
        const int ig = (lane - gb < 9) ? (lane - gb) : 8;
        const int task  = w * 7 + g;
        const int chunk = (task == 0) ? 0 : 1 + (task - 1) / 9;
        const int colj  = (task == 0) ? 0 : (task - 1) % 9;
        const int base  = chunk * 64;
        const bool rn_ok = (task == 0) || (base < len);

        float tc[9];
        #pragma unroll
        for (int k = 0; k < 9; ++k) tc[k] = __expf(trS[k * 9 + ig]);

        const float* lp = logits + (size_t)row * Ls * Kk + base * Kk + ig;
        float f = (task == 0) ? __expf(lp[0]) : ((ig == colj) ? 1.f : 0.f);
        float C = 0.f;

        float a0 = lp[0],      a1 = lp[9 * 1],  a2 = lp[9 * 2],  a3 = lp[9 * 3];
        float a4 = lp[9 * 4],  a5 = lp[9 * 5],  a6 = lp[9 * 6],  a7 = lp[9 * 7];

        #pragma unroll 1
        for (int kk = 0; kk < 8; ++kk) {
            const int nb = 8 * kk + 8;
            const float b0 = lp[9 * MN63(nb + 0)], b1 = lp[9 * MN63(nb + 1)];
            const float b2 = lp[9 * MN63(nb + 2)], b3 = lp[9 * MN63(nb + 3)];
            const float b4 = lp[9 * MN63(nb + 4)], b5 = lp[9 * MN63(nb + 5)];
            const float b6 = lp[9 * MN63(nb + 6)], b7 = lp[9 * MN63(nb + 7)];
            const int sb = 8 * kk;
            GSTEP(a0, sb + 0) GSTEP(a1, sb + 1) GSTEP(a2, sb + 2) GSTEP(a3, sb + 3)
            GSTEP(a4, sb + 4) GSTEP(a5, sb + 5) GSTEP(a6, sb + 6) GSTEP(a7, sb + 7)
            GRN()
            a0 = b0; a1 = b1; a2 = b2; a3 = b3;
            a4 = b4; a5 = b5; a6 = b6; a7 = b7;
        }

        if (act) {
            fS[task][ig] = f;
            if (ig == 0) fS[task][9] = C;
        }
    } else {
        const int4 lb = ((const int4*)(labels + (size_t)row * Ls))[lane];
        const int t0 = lane * 4;
        int la[5];
        la[0] = lb.x; la[1] = lb.y; la[2] = lb.z; la[3] = lb.w;
        la[4] = (t0 + 4 < Ls) ? labels[(size_t)row * Ls + t0 + 4] : 0;
        const float* lgrow = logits + (size_t)row * Ls * Kk;
        float sc = 0.f;
        #pragma unroll
        for (int q = 0; q < 4; ++q) {
            const int t = t0 + q;
            if (t < len) sc += lgrow[t * Kk + la[q]];
            if (t < len - 1) sc += trS[la[q] * Kk + la[q + 1]];
        }
        #pragma unroll
        for (int off = 1; off < 64; off <<= 1) sc += __shfl_xor(sc, off);
        if (lane == 0) scoreS = sc;
    }
    __syncthreads();

    if (w == 0) {
        const int i9 = (lane < 9) ? lane : 0;
        float v = (lane < 9) ? fS[0][lane] : 0.f;
        float Ct = fS[0][9];

        #pragma unroll
        for (int cc = 1; cc <= 3; ++cc) {
            const int tb = 1 + 9 * (cc - 1);
            float Cc[9];
            #pragma unroll
            for (int j = 0; j < 9; ++j) Cc[j] = fS[tb + j][9];
            float Cm = Cc[0];
            #pragma unroll
            for (int j = 1; j < 9; ++j) Cm = fmaxf(Cm, Cc[j]);
            const float u0 = RDLV(v, 0), u1 = RDLV(v, 1), u2 = RDLV(v, 2);
            const float u3 = RDLV(v, 3), u4 = RDLV(v, 4), u5 = RDLV(v, 5);
            const float u6 = RDLV(v, 6), u7 = RDLV(v, 7), u8 = RDLV(v, 8);
            float vo = 0.f;
            vo = fmaf(fS[tb + 0][i9], __expf(Cc[0] - Cm) * u0, vo);
            vo = fmaf(fS[tb + 1][i9], __expf(Cc[1] - Cm) * u1, vo);
            vo = fmaf(fS[tb + 2][i9], __expf(Cc[2] - Cm) * u2, vo);
            vo = fmaf(fS[tb + 3][i9], __expf(Cc[3] - Cm) * u3, vo);
            vo = fmaf(fS[tb + 4][i9], __expf(Cc[4] - Cm) * u4, vo);
            vo = fmaf(fS[tb + 5][i9], __expf(Cc[5] - Cm) * u5, vo);
            vo = fmaf(fS[tb + 6][i9], __expf(Cc[6] - Cm) * u6, vo);
            vo = fmaf(fS[tb + 7][i9], __expf(Cc[7] - Cm) * u7, vo);
            vo = fmaf(fS[tb + 8][i9], __expf(Cc[8] - Cm) * u8, vo);
            v = (lane < 9) ? vo : 0.f;
            Ct += Cm;
        }

        float sum = v;
        sum += __shfl_xor(sum, 1, 16);
        sum += __shfl_xor(sum, 2, 16);
        sum += __shfl_xor(sum, 4, 16);
        sum += __shfl_xor(sum, 8, 16);
        if (lane == 0) ll_out[row] = scoreS - (Ct + __logf(sum));
    }
}

extern "C" void kernel_launch(void* const* d_in, const int* in_sizes, int n_in,
                              void* d_out, int out_size, void* d_ws, size_t ws_size,
                              hipStream_t stream) {
    const int*   text   = (const int*)d_in[0];
    const int*   labels = (const int*)d_in[1];
    const float* embed  = (const float*)d_in[2];
    const float* w1 = (const float*)d_in[3];
    const float* b1 = (const float*)d_in[4];
    const float* w2 = (const float*)d_in[5];
    const float* b2 = (const float*)d_in[6];
    const float* w3 = (const float*)d_in[7];
    const float* b3 = (const float*)d_in[8];
    const float* wd = (const float*)d_in[9];
    const float* bd = (const float*)d_in[10];
    const float* trans = (const float*)d_in[11];

    float* out      = (float*)d_out;
    float* logits   = out;
    float* lens_out = out + (size_t)Bb * Ls * Kk;
    float* ll_out   = lens_out + Bb;
    uint4* wfrag    = (uint4*)d_ws;     // 196 KiB

    hipLaunchKernelGGL(kw_prep, dim3(49), dim3(256), 0, stream, w1, w2, w3, wd, wfrag);
    hipLaunchKernelGGL(kmain, dim3(Ls / 64, Bb), dim3(256), 0, stream,
                       text, embed, wfrag, b1, b2, b3, bd, logits);
    hipLaunchKernelGGL(kc_fused, dim3(Bb), dim3(320), 0, stream,
                       text, labels, trans, logits, lens_out, ll_out);
}